// Round 5
// baseline (778.570 us; speedup 1.0000x reference)
//
#include <hip/hip_runtime.h>
#include <hip/hip_bf16.h>

#define NN 20000
#define IN 128
#define HH 2
#define DD 32
#define HD 64
#define KK 3
#define RR 5
#define EE 320000
#define NEG 0.2f

#define PADK 136
#define NB 313     // buckets per relation (64 dsts each)
#define CAP 2048   // max edges per bucket (mean 1024, sd 32)

typedef short v8s __attribute__((ext_vector_type(8)));
typedef float v4f __attribute__((ext_vector_type(4)));

__device__ __forceinline__ ushort f2b(float f) {
    unsigned u = __float_as_uint(f);
    unsigned r = (u + 0x7fff + ((u >> 16) & 1)) >> 16;   // RNE
    return (ushort)r;
}
__device__ __forceinline__ ushort f2h(float f) {
    _Float16 h = (_Float16)f;
    return __builtin_bit_cast(ushort, h);
}
__device__ __forceinline__ float h2f(ushort u) {
    _Float16 h = __builtin_bit_cast(_Float16, u);
    return (float)h;
}

// ---------------------------------------------------------------------------
// K0a: h (fp32) -> hb (bf16) for MFMA A
// ---------------------------------------------------------------------------
__global__ __launch_bounds__(256) void cvt_h_kernel(
    const float* __restrict__ h, ushort* __restrict__ hb)
{
    int i = blockIdx.x * 256 + threadIdx.x;
    if (i >= NN * IN / 4) return;
    float4 v = ((const float4*)h)[i];
    ((ushort4*)hb)[i] = make_ushort4(f2b(v.x), f2b(v.y), f2b(v.z), f2b(v.w));
}

// ---------------------------------------------------------------------------
// K0b: weights -> wb bf16, transposed+fused: wb[r][col][k], col<64=fc else res
// ---------------------------------------------------------------------------
__global__ __launch_bounds__(256) void cvt_w_kernel(
    const float* __restrict__ fcw, const float* __restrict__ resw,
    ushort* __restrict__ wb)
{
    int i = blockIdx.x * 256 + threadIdx.x;
    if (i >= RR * 128 * IN) return;
    int k = i & 127;
    int c = (i >> 7) & 127;
    int r = i >> 14;
    float v = (c < HD) ? fcw[(r * IN + k) * HD + c] : resw[(r * IN + k) * HD + (c - HD)];
    wb[i] = f2b(v);
}

// ---------------------------------------------------------------------------
// K1: projection via bf16 MFMA; emits fp32 hop0 + res and fp16 table t0.
// ---------------------------------------------------------------------------
__global__ __launch_bounds__(256) void proj_mfma(
    const ushort* __restrict__ hb, const ushort* __restrict__ wb,
    float* __restrict__ hops, float* __restrict__ res,
    ushort* __restrict__ t0)
{
    __shared__ ushort As[64 * PADK];
    __shared__ ushort Bs[128 * PADK];
    int bx = blockIdx.x;
    int r = bx / 313;
    int tile = bx - r * 313;
    int n0 = tile * 64;
    int tid = threadIdx.x;

    #pragma unroll
    for (int i = 0; i < 4; i++) {
        int c = tid + 256 * i;
        int row = c >> 4;
        int off = (c & 15) * 8;
        int gn = n0 + row;
        uint4 v = make_uint4(0, 0, 0, 0);
        if (gn < NN) v = *(const uint4*)&hb[gn * IN + off];
        *(uint4*)&As[row * PADK + off] = v;
    }
    const ushort* wr = wb + (size_t)r * 128 * IN;
    #pragma unroll
    for (int i = 0; i < 8; i++) {
        int c = tid + 256 * i;
        int row = c >> 4;
        int off = (c & 15) * 8;
        *(uint4*)&Bs[row * PADK + off] = *(const uint4*)&wr[row * IN + off];
    }
    __syncthreads();

    int w = tid >> 6, lane = tid & 63;
    int lm = lane & 15, lq = lane >> 4;

    v4f acc[4][2];
    #pragma unroll
    for (int mt = 0; mt < 4; mt++)
        #pragma unroll
        for (int nt = 0; nt < 2; nt++) acc[mt][nt] = (v4f){0.f, 0.f, 0.f, 0.f};

    const ushort* Ab = &As[lm * PADK + lq * 8];
    const ushort* Bb = &Bs[(w * 32 + lm) * PADK + lq * 8];

    #pragma unroll
    for (int ks = 0; ks < 4; ks++) {
        v8s a[4], b[2];
        #pragma unroll
        for (int mt = 0; mt < 4; mt++) a[mt] = *(const v8s*)(Ab + mt * 16 * PADK + ks * 32);
        #pragma unroll
        for (int nt = 0; nt < 2; nt++) b[nt] = *(const v8s*)(Bb + nt * 16 * PADK + ks * 32);
        #pragma unroll
        for (int mt = 0; mt < 4; mt++)
            #pragma unroll
            for (int nt = 0; nt < 2; nt++)
                acc[mt][nt] = __builtin_amdgcn_mfma_f32_16x16x32_bf16(a[mt], b[nt], acc[mt][nt], 0, 0, 0);
    }

    int colbase = w * 32 + lm;
    #pragma unroll
    for (int mt = 0; mt < 4; mt++) {
        #pragma unroll
        for (int nt = 0; nt < 2; nt++) {
            int col = colbase + nt * 16;
            #pragma unroll
            for (int p = 0; p < 4; p++) {
                int node = n0 + mt * 16 + lq * 4 + p;
                if (node < NN) {
                    float v = acc[mt][nt][p];
                    if (col < HD) {
                        hops[((size_t)(r * 4) * NN + node) * HD + col] = v;
                        t0[((size_t)r * NN + node) * HD + col] = f2h(v);
                    } else {
                        res[((size_t)r * NN + node) * HD + (col - HD)] = v;
                    }
                }
            }
        }
    }
}

// ---------------------------------------------------------------------------
// K1b: per-node attention scalars el/er (float2 per (r,n))
// ---------------------------------------------------------------------------
__global__ __launch_bounds__(256) void attn_node_kernel(
    const float* __restrict__ hops, const float* __restrict__ attn_l,
    const float* __restrict__ attn_r, float* __restrict__ el,
    float* __restrict__ er)
{
    int idx = blockIdx.x * 256 + threadIdx.x;
    if (idx >= RR * NN * HH) return;
    int h_ = idx & 1;
    int n = (idx >> 1) % NN;
    int r = idx / (NN * HH);
    const float4* x = (const float4*)(hops + ((size_t)(r * 4) * NN + n) * HD + h_ * DD);
    const float4* al = (const float4*)(attn_l + (r * HH + h_) * DD);
    const float4* ar = (const float4*)(attn_r + (r * HH + h_) * DD);
    float sl = 0.f, sr = 0.f;
    #pragma unroll
    for (int d = 0; d < 8; d++) {
        float4 v = x[d], a = al[d], b = ar[d];
        sl += v.x * a.x + v.y * a.y + v.z * a.z + v.w * a.w;
        sr += v.x * b.x + v.y * b.y + v.z * b.z + v.w * b.w;
    }
    el[idx] = sl;
    er[idx] = sr;
}

// ---------------------------------------------------------------------------
// A1: bucket histogram — LDS-aggregated, 63k global atomics total
// ---------------------------------------------------------------------------
__global__ __launch_bounds__(256) void bhist_kernel(
    const int* __restrict__ dst, int* __restrict__ hist)
{
    __shared__ int hh[NB];
    int r = blockIdx.x >> 7;           // 128 blocks per relation
    int blk = blockIdx.x & 127;
    int tid = threadIdx.x;
    for (int i = tid; i < NB; i += 256) hh[i] = 0;
    __syncthreads();
    const int* D = dst + (size_t)r * EE + blk * 2500;
    for (int i = tid; i < 2500; i += 256)
        atomicAdd(&hh[D[i] >> 6], 1);
    __syncthreads();
    for (int i = tid; i < NB; i += 256)
        if (hh[i]) atomicAdd(&hist[r * NB + i], hh[i]);
}

// ---------------------------------------------------------------------------
// A2: exclusive scan of 313 bucket counts per relation -> bases + cursors
// ---------------------------------------------------------------------------
__global__ __launch_bounds__(64) void bscan_kernel(
    const int* __restrict__ hist, int* __restrict__ bbase,
    int* __restrict__ bcur)
{
    int r = blockIdx.x;
    int t = threadIdx.x;
    int carry = 0;
    for (int c = 0; c < 5; c++) {
        int i = c * 64 + t;
        int v = (i < NB) ? hist[r * NB + i] : 0;
        int x = v;
        #pragma unroll
        for (int off = 1; off < 64; off <<= 1) {
            int tt = __shfl_up(x, off, 64);
            if (t >= off) x += tt;
        }
        if (i < NB) {
            int b = carry + x - v;
            bbase[r * (NB + 1) + i] = b;
            bcur[r * NB + i] = b;
        }
        carry += __shfl(x, 63, 64);
    }
    if (t == 0) bbase[r * (NB + 1) + NB] = carry;
}

// ---------------------------------------------------------------------------
// A3: scatter into bucket regions. Atomics hit 1565 HOT cursors; writes are
// position-sequential per bucket -> L2 line merging. Record = src | dstLow<<15.
// ---------------------------------------------------------------------------
__global__ __launch_bounds__(256) void bscatter_kernel(
    const int* __restrict__ src, const int* __restrict__ dst,
    int* __restrict__ bcur, unsigned* __restrict__ bucketRec)
{
    int idx = blockIdx.x * 256 + threadIdx.x;
    if (idx >= RR * EE) return;
    int r = idx / EE;
    int s = src[idx], d = dst[idx];
    int pos = atomicAdd(&bcur[r * NB + (d >> 6)], 1);
    bucketRec[(size_t)r * EE + pos] = (unsigned)s | ((unsigned)(d & 63) << 15);
}

// ---------------------------------------------------------------------------
// B: per-bucket (64 dsts) LDS counting sort + exact per-dst softmax + final
// csrE {src, half2(w0,w1)} + rowp — ALL global I/O sequential except el gather.
// ---------------------------------------------------------------------------
__global__ __launch_bounds__(256) void bsort_alpha_kernel(
    const unsigned* __restrict__ bucketRec, const int* __restrict__ bbase,
    const float* __restrict__ el, const float* __restrict__ er,
    uint2* __restrict__ csrE, int* __restrict__ rowp)
{
    __shared__ int cnt64s[64];
    __shared__ int segS[65];
    __shared__ int cur[64];
    __shared__ float2 erL[64];
    __shared__ float2 mx2[64];
    __shared__ float2 inv2[64];
    __shared__ unsigned sSD[CAP];
    __shared__ float2 sL[CAP];

    int bk = blockIdx.x;
    int r = bk / NB;
    int bkt = bk - r * NB;
    int tid = threadIdx.x;
    int base = bbase[r * (NB + 1) + bkt];
    int cnt = bbase[r * (NB + 1) + bkt + 1] - base;
    if (cnt > CAP) cnt = CAP;

    if (tid < 64) {
        cnt64s[tid] = 0;
        int gn = bkt * 64 + tid;
        erL[tid] = (gn < NN) ? ((const float2*)er)[(size_t)r * NN + gn]
                             : make_float2(0.f, 0.f);
    }
    __syncthreads();
    const unsigned* BR = bucketRec + (size_t)r * EE + base;
    for (int i = tid; i < cnt; i += 256)
        atomicAdd(&cnt64s[(BR[i] >> 15) & 63], 1);
    __syncthreads();
    if (tid < 64) {
        int v = cnt64s[tid];
        int x = v;
        #pragma unroll
        for (int off = 1; off < 64; off <<= 1) {
            int tt = __shfl_up(x, off, 64);
            if (tid >= off) x += tt;
        }
        segS[tid] = x - v;
        cur[tid] = x - v;
        if (tid == 63) segS[64] = x;
    }
    __syncthreads();
    const float2* el2 = (const float2*)el + (size_t)r * NN;
    for (int i = tid; i < cnt; i += 256) {
        unsigned rec = BR[i];
        int s = rec & 0x7FFF;
        int d = (rec >> 15) & 63;
        float2 a = el2[s];
        float2 b = erL[d];
        float l0 = a.x + b.x; l0 = l0 > 0.f ? l0 : NEG * l0;
        float l1 = a.y + b.y; l1 = l1 > 0.f ? l1 : NEG * l1;
        int pos = atomicAdd(&cur[d], 1);
        sSD[pos] = rec;
        sL[pos] = make_float2(l0, l1);
    }
    __syncthreads();
    if (tid < 64) {
        int b0 = segS[tid], e0 = segS[tid + 1];
        float m0 = -1e30f, m1 = -1e30f;
        for (int i = b0; i < e0; i++) {
            float2 l = sL[i];
            m0 = fmaxf(m0, l.x); m1 = fmaxf(m1, l.y);
        }
        float s0 = 0.f, s1 = 0.f;
        for (int i = b0; i < e0; i++) {
            float2 l = sL[i];
            s0 += __expf(l.x - m0); s1 += __expf(l.y - m1);
        }
        mx2[tid] = make_float2(m0, m1);
        inv2[tid] = make_float2(1.f / fmaxf(s0, 1e-9f), 1.f / fmaxf(s1, 1e-9f));
        int gn = bkt * 64 + tid;
        if (gn < NN) rowp[r * (NN + 1) + gn] = base + segS[tid];
    }
    if (bkt == 0 && tid == 64) rowp[r * (NN + 1) + NN] = EE;
    __syncthreads();
    uint2* E = csrE + (size_t)r * EE + base;
    for (int i = tid; i < cnt; i += 256) {
        unsigned rec = sSD[i];
        int s = rec & 0x7FFF;
        int d = (rec >> 15) & 63;
        float2 l = sL[i];
        float w0 = __expf(l.x - mx2[d].x) * inv2[d].x;
        float w1 = __expf(l.y - mx2[d].y) * inv2[d].y;
        E[i] = make_uint2((unsigned)s, (unsigned)f2h(w0) | ((unsigned)f2h(w1) << 16));
    }
}

// ---------------------------------------------------------------------------
// K6: diffusion hop. Wave per (r,dst); fp16 gather, fp32 accumulate.
// ---------------------------------------------------------------------------
__global__ __launch_bounds__(256) void hop_kernel(
    const ushort* __restrict__ tin, float* __restrict__ hops_k,
    ushort* __restrict__ tout, const uint2* __restrict__ csrE,
    const int* __restrict__ rowp)
{
    int w = (blockIdx.x * 256 + threadIdx.x) >> 6;
    if (w >= RR * NN) return;
    int lane = threadIdx.x & 63;
    int sh = (lane >> 5) * 16;
    int r = w / NN;
    int n = w - r * NN;
    int b = rowp[r * (NN + 1) + n];
    int e = rowp[r * (NN + 1) + n + 1];
    const ushort* T = tin + (size_t)r * NN * HD;
    const uint2* E = csrE + (size_t)r * EE;
    float a0 = 0.f, a1 = 0.f, a2 = 0.f, a3 = 0.f;
    int i = b;
    for (; i + 3 < e; i += 4) {
        uint2 e0 = E[i], e1 = E[i + 1], e2 = E[i + 2], e3 = E[i + 3];
        a0 += h2f((ushort)(e0.y >> sh)) * h2f(T[(size_t)e0.x * HD + lane]);
        a1 += h2f((ushort)(e1.y >> sh)) * h2f(T[(size_t)e1.x * HD + lane]);
        a2 += h2f((ushort)(e2.y >> sh)) * h2f(T[(size_t)e2.x * HD + lane]);
        a3 += h2f((ushort)(e3.y >> sh)) * h2f(T[(size_t)e3.x * HD + lane]);
    }
    for (; i < e; i++) {
        uint2 e0 = E[i];
        a0 += h2f((ushort)(e0.y >> sh)) * h2f(T[(size_t)e0.x * HD + lane]);
    }
    float acc = (a0 + a1) + (a2 + a3);
    __builtin_nontemporal_store(acc, &hops_k[((size_t)(r * 4) * NN + n) * HD + lane]);
    if (tout) tout[((size_t)r * NN + n) * HD + lane] = f2h(acc);
}

// ---------------------------------------------------------------------------
// K7: hop-norm + hop attention + residual + relation combine + head mean
// ---------------------------------------------------------------------------
__device__ __forceinline__ float red32(float v) {
    v += __shfl_xor(v, 16, 64);
    v += __shfl_xor(v, 8, 64);
    v += __shfl_xor(v, 4, 64);
    v += __shfl_xor(v, 2, 64);
    v += __shfl_xor(v, 1, 64);
    return v;
}

__global__ __launch_bounds__(256) void final_kernel(
    const float* __restrict__ hops, const float* __restrict__ res,
    const float* __restrict__ hal, const float* __restrict__ har,
    const float* __restrict__ w_rel, const float* __restrict__ b_rel,
    float* __restrict__ out)
{
    int w = (blockIdx.x * 256 + threadIdx.x) >> 6;
    if (w >= NN) return;
    int lane = threadIdx.x & 63;
    int h_ = lane >> 5;
    int d_ = lane & 31;
    float acc = 0.f;
    #pragma unroll
    for (int r = 0; r < RR; r++) {
        float wr = b_rel[r];
        #pragma unroll
        for (int j = 0; j < RR; j++) wr += w_rel[r * RR + j];
        float halv = hal[(r * HH + h_) * DD + d_];
        float harv = har[(r * HH + h_) * DD + d_];
        float vn[4], lg[4];
        float hr = 0.f;
        #pragma unroll
        for (int kk = 0; kk < 4; kk++) {
            float v = hops[((size_t)(r * 4 + kk) * NN + w) * HD + lane];
            float sq = red32(v * v);
            float inv = 1.f / fmaxf(sqrtf(sq), 1e-9f);
            v *= inv;
            vn[kk] = v;
            lg[kk] = red32(v * halv);
            if (kk == 0) hr = red32(v * harv);
        }
        float mx = -1e30f;
        #pragma unroll
        for (int kk = 0; kk < 4; kk++) {
            float l = lg[kk] + hr;
            l = l > 0.f ? l : NEG * l;
            lg[kk] = l;
            mx = fmaxf(mx, l);
        }
        float s = 0.f;
        #pragma unroll
        for (int kk = 0; kk < 4; kk++) { float ex = __expf(lg[kk] - mx); lg[kk] = ex; s += ex; }
        float o = 0.f;
        #pragma unroll
        for (int kk = 0; kk < 4; kk++) o += lg[kk] * vn[kk];
        o /= s;
        o += res[((size_t)r * NN + w) * HD + lane];
        acc += wr * o;
    }
    float other = __shfl_xor(acc, 32, 64);
    if (lane < 32) out[(size_t)w * DD + d_] = 0.5f * (acc + other);
}

// ---------------------------------------------------------------------------
extern "C" void kernel_launch(void* const* d_in, const int* in_sizes, int n_in,
                              void* d_out, int out_size, void* d_ws, size_t ws_size,
                              hipStream_t stream) {
    (void)in_sizes; (void)n_in; (void)out_size; (void)ws_size;
    const float* h     = (const float*)d_in[0];
    const int*   src   = (const int*)d_in[1];
    const int*   dst   = (const int*)d_in[2];
    const float* fcw   = (const float*)d_in[3];
    const float* resw  = (const float*)d_in[4];
    const float* atl   = (const float*)d_in[5];
    const float* atr   = (const float*)d_in[6];
    const float* hal   = (const float*)d_in[7];
    const float* har   = (const float*)d_in[8];
    const float* wrel  = (const float*)d_in[9];
    const float* brel  = (const float*)d_in[10];
    float* out = (float*)d_out;

    float* ws = (float*)d_ws;
    size_t off = 0;
    float* hops = ws + off;  off += (size_t)RR * 4 * NN * HD;
    float* res  = ws + off;  off += (size_t)RR * NN * HD;
    float* el   = ws + off;  off += (size_t)RR * NN * HH;
    float* er   = ws + off;  off += (size_t)RR * NN * HH;
    uint2* csrE = (uint2*)(ws + off);      off += (size_t)RR * EE * 2;
    unsigned* bucketRec = (unsigned*)(ws + off); off += (size_t)RR * EE;
    ushort* t0  = (ushort*)(ws + off);     off += (size_t)RR * NN * HD / 2;
    ushort* t1  = (ushort*)(ws + off);     off += (size_t)RR * NN * HD / 2;
    ushort* t2  = (ushort*)(ws + off);     off += (size_t)RR * NN * HD / 2;
    ushort* hb  = (ushort*)(ws + off);     off += (size_t)NN * IN / 2;
    ushort* wb  = (ushort*)(ws + off);     off += (size_t)RR * 128 * IN / 2;
    int* rowp   = (int*)(ws + off);  off += (size_t)RR * (NN + 1) + 3;
    int* hist   = (int*)(ws + off);  off += (size_t)RR * NB;
    int* bbase  = (int*)(ws + off);  off += (size_t)RR * (NB + 1);
    int* bcur   = (int*)(ws + off);  off += (size_t)RR * NB;

    hipMemsetAsync(hist, 0, (size_t)RR * NB * sizeof(int), stream);

    cvt_h_kernel<<<(NN * IN / 4 + 255) / 256, 256, 0, stream>>>(h, hb);
    cvt_w_kernel<<<(RR * 128 * IN + 255) / 256, 256, 0, stream>>>(fcw, resw, wb);
    proj_mfma<<<313 * RR, 256, 0, stream>>>(hb, wb, hops, res, t0);
    attn_node_kernel<<<(RR * NN * HH + 255) / 256, 256, 0, stream>>>(hops, atl, atr, el, er);
    bhist_kernel<<<RR * 128, 256, 0, stream>>>(dst, hist);
    bscan_kernel<<<RR, 64, 0, stream>>>(hist, bbase, bcur);
    bscatter_kernel<<<(RR * EE + 255) / 256, 256, 0, stream>>>(src, dst, bcur, bucketRec);
    bsort_alpha_kernel<<<RR * NB, 256, 0, stream>>>(bucketRec, bbase, el, er, csrE, rowp);
    hop_kernel<<<(RR * NN + 3) / 4, 256, 0, stream>>>(t0, hops + (size_t)1 * NN * HD, t1, csrE, rowp);
    hop_kernel<<<(RR * NN + 3) / 4, 256, 0, stream>>>(t1, hops + (size_t)2 * NN * HD, t2, csrE, rowp);
    hop_kernel<<<(RR * NN + 3) / 4, 256, 0, stream>>>(t2, hops + (size_t)3 * NN * HD, nullptr, csrE, rowp);
    final_kernel<<<NN / 4, 256, 0, stream>>>(hops, res, hal, har, wrel, brel, out);
}

// Round 6
// 434.327 us; speedup vs baseline: 1.7926x; 1.7926x over previous
//
#include <hip/hip_runtime.h>
#include <hip/hip_bf16.h>

#define NN 20000
#define IN 128
#define HH 2
#define DD 32
#define HD 64
#define KK 3
#define RR 5
#define EE 320000
#define NEG 0.2f

#define PADK 136
#define NB 313     // buckets per relation (64 dsts each)
#define NBLK 64    // partition blocks per relation
#define CHUNK 5000 // EE / NBLK
#define CAP 2048   // max edges per bucket (mean 1024, sd ~32)

typedef short v8s __attribute__((ext_vector_type(8)));
typedef float v4f __attribute__((ext_vector_type(4)));

__device__ __forceinline__ ushort f2b(float f) {
    unsigned u = __float_as_uint(f);
    unsigned r = (u + 0x7fff + ((u >> 16) & 1)) >> 16;   // RNE
    return (ushort)r;
}
__device__ __forceinline__ ushort f2h(float f) {
    _Float16 h = (_Float16)f;
    return __builtin_bit_cast(ushort, h);
}
__device__ __forceinline__ float h2f(ushort u) {
    _Float16 h = __builtin_bit_cast(_Float16, u);
    return (float)h;
}

// ---------------------------------------------------------------------------
// K0a: h (fp32) -> hb (bf16) for MFMA A
// ---------------------------------------------------------------------------
__global__ __launch_bounds__(256) void cvt_h_kernel(
    const float* __restrict__ h, ushort* __restrict__ hb)
{
    int i = blockIdx.x * 256 + threadIdx.x;
    if (i >= NN * IN / 4) return;
    float4 v = ((const float4*)h)[i];
    ((ushort4*)hb)[i] = make_ushort4(f2b(v.x), f2b(v.y), f2b(v.z), f2b(v.w));
}

// ---------------------------------------------------------------------------
// K0b: weights -> wb bf16, transposed+fused: wb[r][col][k], col<64=fc else res
// ---------------------------------------------------------------------------
__global__ __launch_bounds__(256) void cvt_w_kernel(
    const float* __restrict__ fcw, const float* __restrict__ resw,
    ushort* __restrict__ wb)
{
    int i = blockIdx.x * 256 + threadIdx.x;
    if (i >= RR * 128 * IN) return;
    int k = i & 127;
    int c = (i >> 7) & 127;
    int r = i >> 14;
    float v = (c < HD) ? fcw[(r * IN + k) * HD + c] : resw[(r * IN + k) * HD + (c - HD)];
    wb[i] = f2b(v);
}

// ---------------------------------------------------------------------------
// K1: projection via bf16 MFMA; emits fp32 hop0 + res and fp16 table t0.
// ---------------------------------------------------------------------------
__global__ __launch_bounds__(256) void proj_mfma(
    const ushort* __restrict__ hb, const ushort* __restrict__ wb,
    float* __restrict__ hops, float* __restrict__ res,
    ushort* __restrict__ t0)
{
    __shared__ ushort As[64 * PADK];
    __shared__ ushort Bs[128 * PADK];
    int bx = blockIdx.x;
    int r = bx / 313;
    int tile = bx - r * 313;
    int n0 = tile * 64;
    int tid = threadIdx.x;

    #pragma unroll
    for (int i = 0; i < 4; i++) {
        int c = tid + 256 * i;
        int row = c >> 4;
        int off = (c & 15) * 8;
        int gn = n0 + row;
        uint4 v = make_uint4(0, 0, 0, 0);
        if (gn < NN) v = *(const uint4*)&hb[gn * IN + off];
        *(uint4*)&As[row * PADK + off] = v;
    }
    const ushort* wr = wb + (size_t)r * 128 * IN;
    #pragma unroll
    for (int i = 0; i < 8; i++) {
        int c = tid + 256 * i;
        int row = c >> 4;
        int off = (c & 15) * 8;
        *(uint4*)&Bs[row * PADK + off] = *(const uint4*)&wr[row * IN + off];
    }
    __syncthreads();

    int w = tid >> 6, lane = tid & 63;
    int lm = lane & 15, lq = lane >> 4;

    v4f acc[4][2];
    #pragma unroll
    for (int mt = 0; mt < 4; mt++)
        #pragma unroll
        for (int nt = 0; nt < 2; nt++) acc[mt][nt] = (v4f){0.f, 0.f, 0.f, 0.f};

    const ushort* Ab = &As[lm * PADK + lq * 8];
    const ushort* Bb = &Bs[(w * 32 + lm) * PADK + lq * 8];

    #pragma unroll
    for (int ks = 0; ks < 4; ks++) {
        v8s a[4], b[2];
        #pragma unroll
        for (int mt = 0; mt < 4; mt++) a[mt] = *(const v8s*)(Ab + mt * 16 * PADK + ks * 32);
        #pragma unroll
        for (int nt = 0; nt < 2; nt++) b[nt] = *(const v8s*)(Bb + nt * 16 * PADK + ks * 32);
        #pragma unroll
        for (int mt = 0; mt < 4; mt++)
            #pragma unroll
            for (int nt = 0; nt < 2; nt++)
                acc[mt][nt] = __builtin_amdgcn_mfma_f32_16x16x32_bf16(a[mt], b[nt], acc[mt][nt], 0, 0, 0);
    }

    int colbase = w * 32 + lm;
    #pragma unroll
    for (int mt = 0; mt < 4; mt++) {
        #pragma unroll
        for (int nt = 0; nt < 2; nt++) {
            int col = colbase + nt * 16;
            #pragma unroll
            for (int p = 0; p < 4; p++) {
                int node = n0 + mt * 16 + lq * 4 + p;
                if (node < NN) {
                    float v = acc[mt][nt][p];
                    if (col < HD) {
                        hops[((size_t)(r * 4) * NN + node) * HD + col] = v;
                        t0[((size_t)r * NN + node) * HD + col] = f2h(v);
                    } else {
                        res[((size_t)r * NN + node) * HD + (col - HD)] = v;
                    }
                }
            }
        }
    }
}

// ---------------------------------------------------------------------------
// K1b: per-node attention scalars el/er (float2 per (r,n))
// ---------------------------------------------------------------------------
__global__ __launch_bounds__(256) void attn_node_kernel(
    const float* __restrict__ hops, const float* __restrict__ attn_l,
    const float* __restrict__ attn_r, float* __restrict__ el,
    float* __restrict__ er)
{
    int idx = blockIdx.x * 256 + threadIdx.x;
    if (idx >= RR * NN * HH) return;
    int h_ = idx & 1;
    int n = (idx >> 1) % NN;
    int r = idx / (NN * HH);
    const float4* x = (const float4*)(hops + ((size_t)(r * 4) * NN + n) * HD + h_ * DD);
    const float4* al = (const float4*)(attn_l + (r * HH + h_) * DD);
    const float4* ar = (const float4*)(attn_r + (r * HH + h_) * DD);
    float sl = 0.f, sr = 0.f;
    #pragma unroll
    for (int d = 0; d < 8; d++) {
        float4 v = x[d], a = al[d], b = ar[d];
        sl += v.x * a.x + v.y * a.y + v.z * a.z + v.w * a.w;
        sr += v.x * b.x + v.y * b.y + v.z * b.z + v.w * b.w;
    }
    el[idx] = sl;
    er[idx] = sr;
}

// ---------------------------------------------------------------------------
// A1: per-(relation, block) histogram of 313 buckets over a 5000-edge chunk.
// Deterministic output blkHist[r][bkt][blk]; NO global atomics.
// ---------------------------------------------------------------------------
__global__ __launch_bounds__(256) void bhist_kernel(
    const int* __restrict__ dst, int* __restrict__ blkHist)
{
    __shared__ int hh[NB];
    int r = blockIdx.x >> 6;
    int blk = blockIdx.x & 63;
    int tid = threadIdx.x;
    for (int i = tid; i < NB; i += 256) hh[i] = 0;
    __syncthreads();
    const int* D = dst + (size_t)r * EE + blk * CHUNK;
    for (int i = tid; i < CHUNK; i += 256)
        atomicAdd(&hh[D[i] >> 6], 1);
    __syncthreads();
    for (int i = tid; i < NB; i += 256)
        blkHist[((size_t)(r * NB + i)) * NBLK + blk] = hh[i];
}

// ---------------------------------------------------------------------------
// A2: per-relation exclusive scan over the (bkt-major, blk-minor) 20032-entry
// matrix, in place. Also emits bbase[r][bkt] (= prefix at blk==0) and the
// sentinel bbase[r][NB] = EE.
// ---------------------------------------------------------------------------
__global__ __launch_bounds__(256) void mscan_kernel(
    int* __restrict__ blkHist, int* __restrict__ bbase)
{
    __shared__ int wsum[4];
    __shared__ int carry;
    int r = blockIdx.x;
    int tid = threadIdx.x;
    int lane = tid & 63, w = tid >> 6;
    if (tid == 0) carry = 0;
    __syncthreads();
    int4* B4 = (int4*)(blkHist + (size_t)r * NB * NBLK);
    const int M4 = NB * NBLK / 4;   // 5008
    for (int base = 0; base < M4; base += 256) {
        int i4 = base + tid;
        int4 v = (i4 < M4) ? B4[i4] : make_int4(0, 0, 0, 0);
        int s = v.x + v.y + v.z + v.w;
        int x = s;
        #pragma unroll
        for (int off = 1; off < 64; off <<= 1) {
            int t = __shfl_up(x, off, 64);
            if (lane >= off) x += t;
        }
        if (lane == 63) wsum[w] = x;
        __syncthreads();
        int add = carry;
        for (int j = 0; j < w; j++) add += wsum[j];
        int px = add + x - s;
        if (i4 < M4) {
            int p0 = px, p1 = px + v.x, p2 = p1 + v.y, p3 = p2 + v.z;
            B4[i4] = make_int4(p0, p1, p2, p3);
            int e0 = i4 * 4;
            int pr[4] = {p0, p1, p2, p3};
            #pragma unroll
            for (int k = 0; k < 4; k++) {
                int e = e0 + k;
                if ((e & (NBLK - 1)) == 0) bbase[r * (NB + 1) + (e >> 6)] = pr[k];
            }
        }
        __syncthreads();
        if (tid == 255) carry += wsum[0] + wsum[1] + wsum[2] + wsum[3];
        __syncthreads();
    }
    if (tid == 0) bbase[r * (NB + 1) + NB] = EE;
}

// ---------------------------------------------------------------------------
// A3: partition scatter. Each block owns exclusive slot ranges (from mscan);
// position allocation via LDS atomics only. Record = src | dstLow<<15.
// ---------------------------------------------------------------------------
__global__ __launch_bounds__(256) void bscatter_kernel(
    const int* __restrict__ src, const int* __restrict__ dst,
    const int* __restrict__ blkHist, unsigned* __restrict__ bucketRec)
{
    __shared__ int cur[NB];
    int r = blockIdx.x >> 6;
    int blk = blockIdx.x & 63;
    int tid = threadIdx.x;
    for (int i = tid; i < NB; i += 256)
        cur[i] = blkHist[((size_t)(r * NB + i)) * NBLK + blk];
    __syncthreads();
    const int* S = src + (size_t)r * EE + blk * CHUNK;
    const int* D = dst + (size_t)r * EE + blk * CHUNK;
    unsigned* BR = bucketRec + (size_t)r * EE;
    for (int i = tid; i < CHUNK; i += 256) {
        int s = S[i], d = D[i];
        int pos = atomicAdd(&cur[d >> 6], 1);
        BR[pos] = (unsigned)s | ((unsigned)(d & 63) << 15);
    }
}

// ---------------------------------------------------------------------------
// B: per-bucket (64 dsts) LDS counting sort + exact per-dst softmax + final
// csrE {src, half2(w0,w1)} + rowp — global I/O sequential except el gather.
// ---------------------------------------------------------------------------
__global__ __launch_bounds__(256) void bsort_alpha_kernel(
    const unsigned* __restrict__ bucketRec, const int* __restrict__ bbase,
    const float* __restrict__ el, const float* __restrict__ er,
    uint2* __restrict__ csrE, int* __restrict__ rowp)
{
    __shared__ int cnt64s[64];
    __shared__ int segS[65];
    __shared__ int cur[64];
    __shared__ float2 erL[64];
    __shared__ float2 mx2[64];
    __shared__ float2 inv2[64];
    __shared__ unsigned sSD[CAP];
    __shared__ float2 sL[CAP];

    int bk = blockIdx.x;
    int r = bk / NB;
    int bkt = bk - r * NB;
    int tid = threadIdx.x;
    int base = bbase[r * (NB + 1) + bkt];
    int cnt = bbase[r * (NB + 1) + bkt + 1] - base;
    if (cnt > CAP) cnt = CAP;

    if (tid < 64) {
        cnt64s[tid] = 0;
        int gn = bkt * 64 + tid;
        erL[tid] = (gn < NN) ? ((const float2*)er)[(size_t)r * NN + gn]
                             : make_float2(0.f, 0.f);
    }
    __syncthreads();
    const unsigned* BR = bucketRec + (size_t)r * EE + base;
    for (int i = tid; i < cnt; i += 256)
        atomicAdd(&cnt64s[(BR[i] >> 15) & 63], 1);
    __syncthreads();
    if (tid < 64) {
        int v = cnt64s[tid];
        int x = v;
        #pragma unroll
        for (int off = 1; off < 64; off <<= 1) {
            int tt = __shfl_up(x, off, 64);
            if (tid >= off) x += tt;
        }
        segS[tid] = x - v;
        cur[tid] = x - v;
        if (tid == 63) segS[64] = x;
    }
    __syncthreads();
    const float2* el2 = (const float2*)el + (size_t)r * NN;
    for (int i = tid; i < cnt; i += 256) {
        unsigned rec = BR[i];
        int s = rec & 0x7FFF;
        int d = (rec >> 15) & 63;
        float2 a = el2[s];
        float2 b = erL[d];
        float l0 = a.x + b.x; l0 = l0 > 0.f ? l0 : NEG * l0;
        float l1 = a.y + b.y; l1 = l1 > 0.f ? l1 : NEG * l1;
        int pos = atomicAdd(&cur[d], 1);
        sSD[pos] = rec;
        sL[pos] = make_float2(l0, l1);
    }
    __syncthreads();
    if (tid < 64) {
        int b0 = segS[tid], e0 = segS[tid + 1];
        float m0 = -1e30f, m1 = -1e30f;
        for (int i = b0; i < e0; i++) {
            float2 l = sL[i];
            m0 = fmaxf(m0, l.x); m1 = fmaxf(m1, l.y);
        }
        float s0 = 0.f, s1 = 0.f;
        for (int i = b0; i < e0; i++) {
            float2 l = sL[i];
            s0 += __expf(l.x - m0); s1 += __expf(l.y - m1);
        }
        mx2[tid] = make_float2(m0, m1);
        inv2[tid] = make_float2(1.f / fmaxf(s0, 1e-9f), 1.f / fmaxf(s1, 1e-9f));
        int gn = bkt * 64 + tid;
        if (gn < NN) rowp[r * (NN + 1) + gn] = base + segS[tid];
    }
    if (bkt == 0 && tid == 64) rowp[r * (NN + 1) + NN] = EE;
    __syncthreads();
    uint2* E = csrE + (size_t)r * EE + base;
    for (int i = tid; i < cnt; i += 256) {
        unsigned rec = sSD[i];
        int s = rec & 0x7FFF;
        int d = (rec >> 15) & 63;
        float2 l = sL[i];
        float w0 = __expf(l.x - mx2[d].x) * inv2[d].x;
        float w1 = __expf(l.y - mx2[d].y) * inv2[d].y;
        E[i] = make_uint2((unsigned)s, (unsigned)f2h(w0) | ((unsigned)f2h(w1) << 16));
    }
}

// ---------------------------------------------------------------------------
// K6: diffusion hop. Wave per (r,dst); fp16 gather, fp32 accumulate.
// ---------------------------------------------------------------------------
__global__ __launch_bounds__(256) void hop_kernel(
    const ushort* __restrict__ tin, float* __restrict__ hops_k,
    ushort* __restrict__ tout, const uint2* __restrict__ csrE,
    const int* __restrict__ rowp)
{
    int w = (blockIdx.x * 256 + threadIdx.x) >> 6;
    if (w >= RR * NN) return;
    int lane = threadIdx.x & 63;
    int sh = (lane >> 5) * 16;
    int r = w / NN;
    int n = w - r * NN;
    int b = rowp[r * (NN + 1) + n];
    int e = rowp[r * (NN + 1) + n + 1];
    const ushort* T = tin + (size_t)r * NN * HD;
    const uint2* E = csrE + (size_t)r * EE;
    float a0 = 0.f, a1 = 0.f, a2 = 0.f, a3 = 0.f;
    int i = b;
    for (; i + 3 < e; i += 4) {
        uint2 e0 = E[i], e1 = E[i + 1], e2 = E[i + 2], e3 = E[i + 3];
        a0 += h2f((ushort)(e0.y >> sh)) * h2f(T[(size_t)e0.x * HD + lane]);
        a1 += h2f((ushort)(e1.y >> sh)) * h2f(T[(size_t)e1.x * HD + lane]);
        a2 += h2f((ushort)(e2.y >> sh)) * h2f(T[(size_t)e2.x * HD + lane]);
        a3 += h2f((ushort)(e3.y >> sh)) * h2f(T[(size_t)e3.x * HD + lane]);
    }
    for (; i < e; i++) {
        uint2 e0 = E[i];
        a0 += h2f((ushort)(e0.y >> sh)) * h2f(T[(size_t)e0.x * HD + lane]);
    }
    float acc = (a0 + a1) + (a2 + a3);
    __builtin_nontemporal_store(acc, &hops_k[((size_t)(r * 4) * NN + n) * HD + lane]);
    if (tout) tout[((size_t)r * NN + n) * HD + lane] = f2h(acc);
}

// ---------------------------------------------------------------------------
// K7: hop-norm + hop attention + residual + relation combine + head mean
// ---------------------------------------------------------------------------
__device__ __forceinline__ float red32(float v) {
    v += __shfl_xor(v, 16, 64);
    v += __shfl_xor(v, 8, 64);
    v += __shfl_xor(v, 4, 64);
    v += __shfl_xor(v, 2, 64);
    v += __shfl_xor(v, 1, 64);
    return v;
}

__global__ __launch_bounds__(256) void final_kernel(
    const float* __restrict__ hops, const float* __restrict__ res,
    const float* __restrict__ hal, const float* __restrict__ har,
    const float* __restrict__ w_rel, const float* __restrict__ b_rel,
    float* __restrict__ out)
{
    int w = (blockIdx.x * 256 + threadIdx.x) >> 6;
    if (w >= NN) return;
    int lane = threadIdx.x & 63;
    int h_ = lane >> 5;
    int d_ = lane & 31;
    float acc = 0.f;
    #pragma unroll
    for (int r = 0; r < RR; r++) {
        float wr = b_rel[r];
        #pragma unroll
        for (int j = 0; j < RR; j++) wr += w_rel[r * RR + j];
        float halv = hal[(r * HH + h_) * DD + d_];
        float harv = har[(r * HH + h_) * DD + d_];
        float vn[4], lg[4];
        float hr = 0.f;
        #pragma unroll
        for (int kk = 0; kk < 4; kk++) {
            float v = hops[((size_t)(r * 4 + kk) * NN + w) * HD + lane];
            float sq = red32(v * v);
            float inv = 1.f / fmaxf(sqrtf(sq), 1e-9f);
            v *= inv;
            vn[kk] = v;
            lg[kk] = red32(v * halv);
            if (kk == 0) hr = red32(v * harv);
        }
        float mx = -1e30f;
        #pragma unroll
        for (int kk = 0; kk < 4; kk++) {
            float l = lg[kk] + hr;
            l = l > 0.f ? l : NEG * l;
            lg[kk] = l;
            mx = fmaxf(mx, l);
        }
        float s = 0.f;
        #pragma unroll
        for (int kk = 0; kk < 4; kk++) { float ex = __expf(lg[kk] - mx); lg[kk] = ex; s += ex; }
        float o = 0.f;
        #pragma unroll
        for (int kk = 0; kk < 4; kk++) o += lg[kk] * vn[kk];
        o /= s;
        o += res[((size_t)r * NN + w) * HD + lane];
        acc += wr * o;
    }
    float other = __shfl_xor(acc, 32, 64);
    if (lane < 32) out[(size_t)w * DD + d_] = 0.5f * (acc + other);
}

// ---------------------------------------------------------------------------
extern "C" void kernel_launch(void* const* d_in, const int* in_sizes, int n_in,
                              void* d_out, int out_size, void* d_ws, size_t ws_size,
                              hipStream_t stream) {
    (void)in_sizes; (void)n_in; (void)out_size; (void)ws_size;
    const float* h     = (const float*)d_in[0];
    const int*   src   = (const int*)d_in[1];
    const int*   dst   = (const int*)d_in[2];
    const float* fcw   = (const float*)d_in[3];
    const float* resw  = (const float*)d_in[4];
    const float* atl   = (const float*)d_in[5];
    const float* atr   = (const float*)d_in[6];
    const float* hal   = (const float*)d_in[7];
    const float* har   = (const float*)d_in[8];
    const float* wrel  = (const float*)d_in[9];
    const float* brel  = (const float*)d_in[10];
    float* out = (float*)d_out;

    float* ws = (float*)d_ws;
    size_t off = 0;
    float* hops = ws + off;  off += (size_t)RR * 4 * NN * HD;
    float* res  = ws + off;  off += (size_t)RR * NN * HD;
    float* el   = ws + off;  off += (size_t)RR * NN * HH;
    float* er   = ws + off;  off += (size_t)RR * NN * HH;
    uint2* csrE = (uint2*)(ws + off);      off += (size_t)RR * EE * 2;
    unsigned* bucketRec = (unsigned*)(ws + off); off += (size_t)RR * EE;
    ushort* t0  = (ushort*)(ws + off);     off += (size_t)RR * NN * HD / 2;
    ushort* t1  = (ushort*)(ws + off);     off += (size_t)RR * NN * HD / 2;
    ushort* t2  = (ushort*)(ws + off);     off += (size_t)RR * NN * HD / 2;
    ushort* hb  = (ushort*)(ws + off);     off += (size_t)NN * IN / 2;
    ushort* wb  = (ushort*)(ws + off);     off += (size_t)RR * 128 * IN / 2;
    int* rowp   = (int*)(ws + off);  off += (size_t)RR * (NN + 1) + 3;
    int* blkHist = (int*)(ws + off); off += (size_t)RR * NB * NBLK;
    int* bbase  = (int*)(ws + off);  off += (size_t)RR * (NB + 1);

    cvt_h_kernel<<<(NN * IN / 4 + 255) / 256, 256, 0, stream>>>(h, hb);
    cvt_w_kernel<<<(RR * 128 * IN + 255) / 256, 256, 0, stream>>>(fcw, resw, wb);
    proj_mfma<<<313 * RR, 256, 0, stream>>>(hb, wb, hops, res, t0);
    attn_node_kernel<<<(RR * NN * HH + 255) / 256, 256, 0, stream>>>(hops, atl, atr, el, er);
    bhist_kernel<<<RR * NBLK, 256, 0, stream>>>(dst, blkHist);
    mscan_kernel<<<RR, 256, 0, stream>>>(blkHist, bbase);
    bscatter_kernel<<<RR * NBLK, 256, 0, stream>>>(src, dst, blkHist, bucketRec);
    bsort_alpha_kernel<<<RR * NB, 256, 0, stream>>>(bucketRec, bbase, el, er, csrE, rowp);
    hop_kernel<<<(RR * NN + 3) / 4, 256, 0, stream>>>(t0, hops + (size_t)1 * NN * HD, t1, csrE, rowp);
    hop_kernel<<<(RR * NN + 3) / 4, 256, 0, stream>>>(t1, hops + (size_t)2 * NN * HD, t2, csrE, rowp);
    hop_kernel<<<(RR * NN + 3) / 4, 256, 0, stream>>>(t2, hops + (size_t)3 * NN * HD, nullptr, csrE, rowp);
    final_kernel<<<NN / 4, 256, 0, stream>>>(hops, res, hal, har, wrel, brel, out);
}

// Round 7
// 426.452 us; speedup vs baseline: 1.8257x; 1.0185x over previous
//
#include <hip/hip_runtime.h>
#include <hip/hip_bf16.h>

#define NN 20000
#define IN 128
#define HH 2
#define DD 32
#define HD 64
#define KK 3
#define RR 5
#define EE 320000
#define NEG 0.2f

#define PADK 136
#define NB 313     // buckets per relation (64 dsts each)
#define NBLK 64    // partition blocks per relation
#define CHUNK 5000 // EE / NBLK
#define CAP 2048   // max edges per bucket (mean 1024, sd ~32)

typedef short v8s __attribute__((ext_vector_type(8)));
typedef float v4f __attribute__((ext_vector_type(4)));

__device__ __forceinline__ ushort f2b(float f) {
    unsigned u = __float_as_uint(f);
    unsigned r = (u + 0x7fff + ((u >> 16) & 1)) >> 16;   // RNE
    return (ushort)r;
}
__device__ __forceinline__ ushort f2h(float f) {
    _Float16 h = (_Float16)f;
    return __builtin_bit_cast(ushort, h);
}
__device__ __forceinline__ float h2f(ushort u) {
    _Float16 h = __builtin_bit_cast(_Float16, u);
    return (float)h;
}
__device__ __forceinline__ float2 up2(unsigned u) {
    return make_float2(h2f((ushort)(u & 0xFFFF)), h2f((ushort)(u >> 16)));
}

// ---------------------------------------------------------------------------
// K0a: h (fp32) -> hb (bf16) for MFMA A
// ---------------------------------------------------------------------------
__global__ __launch_bounds__(256) void cvt_h_kernel(
    const float* __restrict__ h, ushort* __restrict__ hb)
{
    int i = blockIdx.x * 256 + threadIdx.x;
    if (i >= NN * IN / 4) return;
    float4 v = ((const float4*)h)[i];
    ((ushort4*)hb)[i] = make_ushort4(f2b(v.x), f2b(v.y), f2b(v.z), f2b(v.w));
}

// ---------------------------------------------------------------------------
// K0b: weights -> wb bf16, transposed+fused: wb[r][col][k], col<64=fc else res
// ---------------------------------------------------------------------------
__global__ __launch_bounds__(256) void cvt_w_kernel(
    const float* __restrict__ fcw, const float* __restrict__ resw,
    ushort* __restrict__ wb)
{
    int i = blockIdx.x * 256 + threadIdx.x;
    if (i >= RR * 128 * IN) return;
    int k = i & 127;
    int c = (i >> 7) & 127;
    int r = i >> 14;
    float v = (c < HD) ? fcw[(r * IN + k) * HD + c] : resw[(r * IN + k) * HD + (c - HD)];
    wb[i] = f2b(v);
}

// ---------------------------------------------------------------------------
// K1: projection via bf16 MFMA; emits fp16 table t0 (x) and fp32 res.
// ---------------------------------------------------------------------------
__global__ __launch_bounds__(256) void proj_mfma(
    const ushort* __restrict__ hb, const ushort* __restrict__ wb,
    ushort* __restrict__ t0, float* __restrict__ res)
{
    __shared__ ushort As[64 * PADK];
    __shared__ ushort Bs[128 * PADK];
    int bx = blockIdx.x;
    int r = bx / 313;
    int tile = bx - r * 313;
    int n0 = tile * 64;
    int tid = threadIdx.x;

    #pragma unroll
    for (int i = 0; i < 4; i++) {
        int c = tid + 256 * i;
        int row = c >> 4;
        int off = (c & 15) * 8;
        int gn = n0 + row;
        uint4 v = make_uint4(0, 0, 0, 0);
        if (gn < NN) v = *(const uint4*)&hb[gn * IN + off];
        *(uint4*)&As[row * PADK + off] = v;
    }
    const ushort* wr = wb + (size_t)r * 128 * IN;
    #pragma unroll
    for (int i = 0; i < 8; i++) {
        int c = tid + 256 * i;
        int row = c >> 4;
        int off = (c & 15) * 8;
        *(uint4*)&Bs[row * PADK + off] = *(const uint4*)&wr[row * IN + off];
    }
    __syncthreads();

    int w = tid >> 6, lane = tid & 63;
    int lm = lane & 15, lq = lane >> 4;

    v4f acc[4][2];
    #pragma unroll
    for (int mt = 0; mt < 4; mt++)
        #pragma unroll
        for (int nt = 0; nt < 2; nt++) acc[mt][nt] = (v4f){0.f, 0.f, 0.f, 0.f};

    const ushort* Ab = &As[lm * PADK + lq * 8];
    const ushort* Bb = &Bs[(w * 32 + lm) * PADK + lq * 8];

    #pragma unroll
    for (int ks = 0; ks < 4; ks++) {
        v8s a[4], b[2];
        #pragma unroll
        for (int mt = 0; mt < 4; mt++) a[mt] = *(const v8s*)(Ab + mt * 16 * PADK + ks * 32);
        #pragma unroll
        for (int nt = 0; nt < 2; nt++) b[nt] = *(const v8s*)(Bb + nt * 16 * PADK + ks * 32);
        #pragma unroll
        for (int mt = 0; mt < 4; mt++)
            #pragma unroll
            for (int nt = 0; nt < 2; nt++)
                acc[mt][nt] = __builtin_amdgcn_mfma_f32_16x16x32_bf16(a[mt], b[nt], acc[mt][nt], 0, 0, 0);
    }

    int colbase = w * 32 + lm;
    #pragma unroll
    for (int mt = 0; mt < 4; mt++) {
        #pragma unroll
        for (int nt = 0; nt < 2; nt++) {
            int col = colbase + nt * 16;
            #pragma unroll
            for (int p = 0; p < 4; p++) {
                int node = n0 + mt * 16 + lq * 4 + p;
                if (node < NN) {
                    float v = acc[mt][nt][p];
                    if (col < HD) {
                        t0[((size_t)r * NN + node) * HD + col] = f2h(v);
                    } else {
                        res[((size_t)r * NN + node) * HD + (col - HD)] = v;
                    }
                }
            }
        }
    }
}

// ---------------------------------------------------------------------------
// K1b: per-node attention scalars el/er from fp16 t0
// ---------------------------------------------------------------------------
__global__ __launch_bounds__(256) void attn_node_kernel(
    const ushort* __restrict__ t0, const float* __restrict__ attn_l,
    const float* __restrict__ attn_r, float* __restrict__ el,
    float* __restrict__ er)
{
    int idx = blockIdx.x * 256 + threadIdx.x;
    if (idx >= RR * NN * HH) return;
    int h_ = idx & 1;
    int n = (idx >> 1) % NN;
    int r = idx / (NN * HH);
    const ushort* x = t0 + ((size_t)r * NN + n) * HD + h_ * DD;
    const float* al = attn_l + (r * HH + h_) * DD;
    const float* ar = attn_r + (r * HH + h_) * DD;
    uint4 p0 = *(const uint4*)(x);
    uint4 p1 = *(const uint4*)(x + 8);
    uint4 p2 = *(const uint4*)(x + 16);
    uint4 p3 = *(const uint4*)(x + 24);
    unsigned P[8] = {p0.x, p0.y, p0.z, p0.w, p1.x, p1.y, p1.z, p1.w};
    unsigned Q[8] = {p2.x, p2.y, p2.z, p2.w, p3.x, p3.y, p3.z, p3.w};
    float sl = 0.f, sr = 0.f;
    #pragma unroll
    for (int j = 0; j < 8; j++) {
        float2 v = up2(P[j]);
        sl += v.x * al[2 * j] + v.y * al[2 * j + 1];
        sr += v.x * ar[2 * j] + v.y * ar[2 * j + 1];
    }
    #pragma unroll
    for (int j = 0; j < 8; j++) {
        float2 v = up2(Q[j]);
        sl += v.x * al[16 + 2 * j] + v.y * al[16 + 2 * j + 1];
        sr += v.x * ar[16 + 2 * j] + v.y * ar[16 + 2 * j + 1];
    }
    el[idx] = sl;
    er[idx] = sr;
}

// ---------------------------------------------------------------------------
// A1: per-(relation, block) histogram of 313 buckets over a 5000-edge chunk.
// ---------------------------------------------------------------------------
__global__ __launch_bounds__(256) void bhist_kernel(
    const int* __restrict__ dst, int* __restrict__ blkHist)
{
    __shared__ int hh[NB];
    int r = blockIdx.x >> 6;
    int blk = blockIdx.x & 63;
    int tid = threadIdx.x;
    for (int i = tid; i < NB; i += 256) hh[i] = 0;
    __syncthreads();
    const int* D = dst + (size_t)r * EE + blk * CHUNK;
    for (int i = tid; i < CHUNK; i += 256)
        atomicAdd(&hh[D[i] >> 6], 1);
    __syncthreads();
    for (int i = tid; i < NB; i += 256)
        blkHist[((size_t)(r * NB + i)) * NBLK + blk] = hh[i];
}

// ---------------------------------------------------------------------------
// A2: per-relation exclusive scan over (bkt-major, blk-minor) matrix.
// ---------------------------------------------------------------------------
__global__ __launch_bounds__(256) void mscan_kernel(
    int* __restrict__ blkHist, int* __restrict__ bbase)
{
    __shared__ int wsum[4];
    __shared__ int carry;
    int r = blockIdx.x;
    int tid = threadIdx.x;
    int lane = tid & 63, w = tid >> 6;
    if (tid == 0) carry = 0;
    __syncthreads();
    int4* B4 = (int4*)(blkHist + (size_t)r * NB * NBLK);
    const int M4 = NB * NBLK / 4;   // 5008
    for (int base = 0; base < M4; base += 256) {
        int i4 = base + tid;
        int4 v = (i4 < M4) ? B4[i4] : make_int4(0, 0, 0, 0);
        int s = v.x + v.y + v.z + v.w;
        int x = s;
        #pragma unroll
        for (int off = 1; off < 64; off <<= 1) {
            int t = __shfl_up(x, off, 64);
            if (lane >= off) x += t;
        }
        if (lane == 63) wsum[w] = x;
        __syncthreads();
        int add = carry;
        for (int j = 0; j < w; j++) add += wsum[j];
        int px = add + x - s;
        if (i4 < M4) {
            int p0 = px, p1 = px + v.x, p2 = p1 + v.y, p3 = p2 + v.z;
            B4[i4] = make_int4(p0, p1, p2, p3);
            int e0 = i4 * 4;
            int pr[4] = {p0, p1, p2, p3};
            #pragma unroll
            for (int k = 0; k < 4; k++) {
                int e = e0 + k;
                if ((e & (NBLK - 1)) == 0) bbase[r * (NB + 1) + (e >> 6)] = pr[k];
            }
        }
        __syncthreads();
        if (tid == 255) carry += wsum[0] + wsum[1] + wsum[2] + wsum[3];
        __syncthreads();
    }
    if (tid == 0) bbase[r * (NB + 1) + NB] = EE;
}

// ---------------------------------------------------------------------------
// A3: partition scatter, LDS cursors only, exclusive global slot ranges.
// ---------------------------------------------------------------------------
__global__ __launch_bounds__(256) void bscatter_kernel(
    const int* __restrict__ src, const int* __restrict__ dst,
    const int* __restrict__ blkHist, unsigned* __restrict__ bucketRec)
{
    __shared__ int cur[NB];
    int r = blockIdx.x >> 6;
    int blk = blockIdx.x & 63;
    int tid = threadIdx.x;
    for (int i = tid; i < NB; i += 256)
        cur[i] = blkHist[((size_t)(r * NB + i)) * NBLK + blk];
    __syncthreads();
    const int* S = src + (size_t)r * EE + blk * CHUNK;
    const int* D = dst + (size_t)r * EE + blk * CHUNK;
    unsigned* BR = bucketRec + (size_t)r * EE;
    for (int i = tid; i < CHUNK; i += 256) {
        int s = S[i], d = D[i];
        int pos = atomicAdd(&cur[d >> 6], 1);
        BR[pos] = (unsigned)s | ((unsigned)(d & 63) << 15);
    }
}

// ---------------------------------------------------------------------------
// B: per-bucket LDS counting sort + exact per-dst softmax + csrE + rowp
// ---------------------------------------------------------------------------
__global__ __launch_bounds__(256) void bsort_alpha_kernel(
    const unsigned* __restrict__ bucketRec, const int* __restrict__ bbase,
    const float* __restrict__ el, const float* __restrict__ er,
    uint2* __restrict__ csrE, int* __restrict__ rowp)
{
    __shared__ int cnt64s[64];
    __shared__ int segS[65];
    __shared__ int cur[64];
    __shared__ float2 erL[64];
    __shared__ float2 mx2[64];
    __shared__ float2 inv2[64];
    __shared__ unsigned sSD[CAP];
    __shared__ float2 sL[CAP];

    int bk = blockIdx.x;
    int r = bk / NB;
    int bkt = bk - r * NB;
    int tid = threadIdx.x;
    int base = bbase[r * (NB + 1) + bkt];
    int cnt = bbase[r * (NB + 1) + bkt + 1] - base;
    if (cnt > CAP) cnt = CAP;

    if (tid < 64) {
        cnt64s[tid] = 0;
        int gn = bkt * 64 + tid;
        erL[tid] = (gn < NN) ? ((const float2*)er)[(size_t)r * NN + gn]
                             : make_float2(0.f, 0.f);
    }
    __syncthreads();
    const unsigned* BR = bucketRec + (size_t)r * EE + base;
    for (int i = tid; i < cnt; i += 256)
        atomicAdd(&cnt64s[(BR[i] >> 15) & 63], 1);
    __syncthreads();
    if (tid < 64) {
        int v = cnt64s[tid];
        int x = v;
        #pragma unroll
        for (int off = 1; off < 64; off <<= 1) {
            int tt = __shfl_up(x, off, 64);
            if (tid >= off) x += tt;
        }
        segS[tid] = x - v;
        cur[tid] = x - v;
        if (tid == 63) segS[64] = x;
    }
    __syncthreads();
    const float2* el2 = (const float2*)el + (size_t)r * NN;
    for (int i = tid; i < cnt; i += 256) {
        unsigned rec = BR[i];
        int s = rec & 0x7FFF;
        int d = (rec >> 15) & 63;
        float2 a = el2[s];
        float2 b = erL[d];
        float l0 = a.x + b.x; l0 = l0 > 0.f ? l0 : NEG * l0;
        float l1 = a.y + b.y; l1 = l1 > 0.f ? l1 : NEG * l1;
        int pos = atomicAdd(&cur[d], 1);
        sSD[pos] = rec;
        sL[pos] = make_float2(l0, l1);
    }
    __syncthreads();
    if (tid < 64) {
        int b0 = segS[tid], e0 = segS[tid + 1];
        float m0 = -1e30f, m1 = -1e30f;
        for (int i = b0; i < e0; i++) {
            float2 l = sL[i];
            m0 = fmaxf(m0, l.x); m1 = fmaxf(m1, l.y);
        }
        float s0 = 0.f, s1 = 0.f;
        for (int i = b0; i < e0; i++) {
            float2 l = sL[i];
            s0 += __expf(l.x - m0); s1 += __expf(l.y - m1);
        }
        mx2[tid] = make_float2(m0, m1);
        inv2[tid] = make_float2(1.f / fmaxf(s0, 1e-9f), 1.f / fmaxf(s1, 1e-9f));
        int gn = bkt * 64 + tid;
        if (gn < NN) rowp[r * (NN + 1) + gn] = base + segS[tid];
    }
    if (bkt == 0 && tid == 64) rowp[r * (NN + 1) + NN] = EE;
    __syncthreads();
    uint2* E = csrE + (size_t)r * EE + base;
    for (int i = tid; i < cnt; i += 256) {
        unsigned rec = sSD[i];
        int s = rec & 0x7FFF;
        int d = (rec >> 15) & 63;
        float2 l = sL[i];
        float w0 = __expf(l.x - mx2[d].x) * inv2[d].x;
        float w1 = __expf(l.y - mx2[d].y) * inv2[d].y;
        E[i] = make_uint2((unsigned)s, (unsigned)f2h(w0) | ((unsigned)f2h(w1) << 16));
    }
}

// ---------------------------------------------------------------------------
// K6: diffusion hop. Wave per (r,dst). Edge stream scalarized (SGPR loads);
// fp16 gather with saddr-form addressing; fp16 table out only.
// ---------------------------------------------------------------------------
__global__ __launch_bounds__(256) void hop_kernel(
    const ushort* __restrict__ tin, ushort* __restrict__ tout,
    const uint2* __restrict__ csrE, const int* __restrict__ rowp)
{
    int w = (blockIdx.x * 256 + threadIdx.x) >> 6;
    if (w >= RR * NN) return;
    int lane = threadIdx.x & 63;
    int sh = (lane >> 5) * 16;
    int r = w / NN;
    int n = w - r * NN;
    int b = __builtin_amdgcn_readfirstlane(rowp[r * (NN + 1) + n]);
    int e = __builtin_amdgcn_readfirstlane(rowp[r * (NN + 1) + n + 1]);
    const ushort* T = tin + (size_t)r * NN * HD;
    const uint2* E = csrE + (size_t)r * EE;
    float a0 = 0.f, a1 = 0.f, a2 = 0.f, a3 = 0.f;
    int i = b;
    for (; i + 3 < e; i += 4) {
        uint2 e0 = E[i], e1 = E[i + 1], e2 = E[i + 2], e3 = E[i + 3];
        unsigned s0 = __builtin_amdgcn_readfirstlane(e0.x);
        unsigned s1 = __builtin_amdgcn_readfirstlane(e1.x);
        unsigned s2 = __builtin_amdgcn_readfirstlane(e2.x);
        unsigned s3 = __builtin_amdgcn_readfirstlane(e3.x);
        unsigned w0 = __builtin_amdgcn_readfirstlane(e0.y);
        unsigned w1 = __builtin_amdgcn_readfirstlane(e1.y);
        unsigned w2 = __builtin_amdgcn_readfirstlane(e2.y);
        unsigned w3 = __builtin_amdgcn_readfirstlane(e3.y);
        const ushort* T0 = T + (size_t)s0 * HD;
        const ushort* T1 = T + (size_t)s1 * HD;
        const ushort* T2 = T + (size_t)s2 * HD;
        const ushort* T3 = T + (size_t)s3 * HD;
        a0 += h2f((ushort)(w0 >> sh)) * h2f(T0[lane]);
        a1 += h2f((ushort)(w1 >> sh)) * h2f(T1[lane]);
        a2 += h2f((ushort)(w2 >> sh)) * h2f(T2[lane]);
        a3 += h2f((ushort)(w3 >> sh)) * h2f(T3[lane]);
    }
    for (; i < e; i++) {
        uint2 e0 = E[i];
        unsigned s0 = __builtin_amdgcn_readfirstlane(e0.x);
        unsigned w0 = __builtin_amdgcn_readfirstlane(e0.y);
        const ushort* T0 = T + (size_t)s0 * HD;
        a0 += h2f((ushort)(w0 >> sh)) * h2f(T0[lane]);
    }
    float acc = (a0 + a1) + (a2 + a3);
    tout[((size_t)r * NN + n) * HD + lane] = f2h(acc);
}

// ---------------------------------------------------------------------------
// K7: hop-norm + hop attention + residual + relation combine + head mean.
// Hops read from fp16 tables t0..t3.
// ---------------------------------------------------------------------------
__device__ __forceinline__ float red32(float v) {
    v += __shfl_xor(v, 16, 64);
    v += __shfl_xor(v, 8, 64);
    v += __shfl_xor(v, 4, 64);
    v += __shfl_xor(v, 2, 64);
    v += __shfl_xor(v, 1, 64);
    return v;
}

__global__ __launch_bounds__(256) void final_kernel(
    const ushort* __restrict__ t0, const ushort* __restrict__ t1,
    const ushort* __restrict__ t2, const ushort* __restrict__ t3,
    const float* __restrict__ res,
    const float* __restrict__ hal, const float* __restrict__ har,
    const float* __restrict__ w_rel, const float* __restrict__ b_rel,
    float* __restrict__ out)
{
    int w = (blockIdx.x * 256 + threadIdx.x) >> 6;
    if (w >= NN) return;
    int lane = threadIdx.x & 63;
    int h_ = lane >> 5;
    int d_ = lane & 31;
    const ushort* tb[4] = {t0, t1, t2, t3};
    float acc = 0.f;
    #pragma unroll
    for (int r = 0; r < RR; r++) {
        float wr = b_rel[r];
        #pragma unroll
        for (int j = 0; j < RR; j++) wr += w_rel[r * RR + j];
        float halv = hal[(r * HH + h_) * DD + d_];
        float harv = har[(r * HH + h_) * DD + d_];
        float vn[4], lg[4];
        float hr = 0.f;
        #pragma unroll
        for (int kk = 0; kk < 4; kk++) {
            float v = h2f(tb[kk][((size_t)r * NN + w) * HD + lane]);
            float sq = red32(v * v);
            float inv = 1.f / fmaxf(sqrtf(sq), 1e-9f);
            v *= inv;
            vn[kk] = v;
            lg[kk] = red32(v * halv);
            if (kk == 0) hr = red32(v * harv);
        }
        float mx = -1e30f;
        #pragma unroll
        for (int kk = 0; kk < 4; kk++) {
            float l = lg[kk] + hr;
            l = l > 0.f ? l : NEG * l;
            lg[kk] = l;
            mx = fmaxf(mx, l);
        }
        float s = 0.f;
        #pragma unroll
        for (int kk = 0; kk < 4; kk++) { float ex = __expf(lg[kk] - mx); lg[kk] = ex; s += ex; }
        float o = 0.f;
        #pragma unroll
        for (int kk = 0; kk < 4; kk++) o += lg[kk] * vn[kk];
        o /= s;
        o += res[((size_t)r * NN + w) * HD + lane];
        acc += wr * o;
    }
    float other = __shfl_xor(acc, 32, 64);
    if (lane < 32) out[(size_t)w * DD + d_] = 0.5f * (acc + other);
}

// ---------------------------------------------------------------------------
extern "C" void kernel_launch(void* const* d_in, const int* in_sizes, int n_in,
                              void* d_out, int out_size, void* d_ws, size_t ws_size,
                              hipStream_t stream) {
    (void)in_sizes; (void)n_in; (void)out_size; (void)ws_size;
    const float* h     = (const float*)d_in[0];
    const int*   src   = (const int*)d_in[1];
    const int*   dst   = (const int*)d_in[2];
    const float* fcw   = (const float*)d_in[3];
    const float* resw  = (const float*)d_in[4];
    const float* atl   = (const float*)d_in[5];
    const float* atr   = (const float*)d_in[6];
    const float* hal   = (const float*)d_in[7];
    const float* har   = (const float*)d_in[8];
    const float* wrel  = (const float*)d_in[9];
    const float* brel  = (const float*)d_in[10];
    float* out = (float*)d_out;

    float* ws = (float*)d_ws;
    size_t off = 0;
    float* res  = ws + off;  off += (size_t)RR * NN * HD;
    float* el   = ws + off;  off += (size_t)RR * NN * HH;
    float* er   = ws + off;  off += (size_t)RR * NN * HH;
    uint2* csrE = (uint2*)(ws + off);      off += (size_t)RR * EE * 2;
    unsigned* bucketRec = (unsigned*)(ws + off); off += (size_t)RR * EE;
    ushort* t0  = (ushort*)(ws + off);     off += (size_t)RR * NN * HD / 2;
    ushort* t1  = (ushort*)(ws + off);     off += (size_t)RR * NN * HD / 2;
    ushort* t2  = (ushort*)(ws + off);     off += (size_t)RR * NN * HD / 2;
    ushort* t3  = (ushort*)(ws + off);     off += (size_t)RR * NN * HD / 2;
    ushort* hb  = (ushort*)(ws + off);     off += (size_t)NN * IN / 2;
    ushort* wb  = (ushort*)(ws + off);     off += (size_t)RR * 128 * IN / 2;
    int* rowp   = (int*)(ws + off);  off += (size_t)RR * (NN + 1) + 3;
    int* blkHist = (int*)(ws + off); off += (size_t)RR * NB * NBLK;
    int* bbase  = (int*)(ws + off);  off += (size_t)RR * (NB + 1);

    cvt_h_kernel<<<(NN * IN / 4 + 255) / 256, 256, 0, stream>>>(h, hb);
    cvt_w_kernel<<<(RR * 128 * IN + 255) / 256, 256, 0, stream>>>(fcw, resw, wb);
    proj_mfma<<<313 * RR, 256, 0, stream>>>(hb, wb, t0, res);
    attn_node_kernel<<<(RR * NN * HH + 255) / 256, 256, 0, stream>>>(t0, atl, atr, el, er);
    bhist_kernel<<<RR * NBLK, 256, 0, stream>>>(dst, blkHist);
    mscan_kernel<<<RR, 256, 0, stream>>>(blkHist, bbase);
    bscatter_kernel<<<RR * NBLK, 256, 0, stream>>>(src, dst, blkHist, bucketRec);
    bsort_alpha_kernel<<<RR * NB, 256, 0, stream>>>(bucketRec, bbase, el, er, csrE, rowp);
    hop_kernel<<<(RR * NN + 3) / 4, 256, 0, stream>>>(t0, t1, csrE, rowp);
    hop_kernel<<<(RR * NN + 3) / 4, 256, 0, stream>>>(t1, t2, csrE, rowp);
    hop_kernel<<<(RR * NN + 3) / 4, 256, 0, stream>>>(t2, t3, csrE, rowp);
    final_kernel<<<NN / 4, 256, 0, stream>>>(t0, t1, t2, t3, res, hal, har, wrel, brel, out);
}